// Round 8
// baseline (228.266 us; speedup 1.0000x reference)
//
#include <hip/hip_runtime.h>
#include <hip/hip_cooperative_groups.h>
#include <math.h>

namespace cg = cooperative_groups;

#define TANFOV 1.0f

// AoS gaussian record: 3 x float4
//   [0] = (tz, -0.5*conA, -conB, -0.5*conC)
//   [1] = (mx, my, op(0 if invalid), 0)
//   [2] = (c0, c1, c2, 0)
#define REC   12     // floats per gaussian
#define CHG   256    // gaussians per chunk (== block size)
#define SEG_L 128    // sort segment length
#define GPB_MAX 8    // max gaussians preprocessed per block

// ---------------------------------------------------------------------------
// Single cooperative kernel, 5 phases separated by grid.sync():
//  P1 preprocess (4 gaussians/block, frest LDS-staged)  -> pre,bbox,tz,radii
//  P2 sort partial-rank count (128 block-tasks)         -> rankpart
//  P3 rank sum + scatter (8 blocks)                     -> srt,bboxsrt
//  P4 tile-cull blend, one (16x16 tile, 256-chunk)/block-> part
//  P5 per-tile chunk combine (64 blocks)                -> out
// grid = NT*G = 512 blocks x 256 threads; __launch_bounds__(256,2) + ~15KB
// LDS guarantees >=2 blocks/CU so 512 blocks are co-resident on 256 CUs.
// ---------------------------------------------------------------------------
__global__ __launch_bounds__(256, 2)
void render_coop_kernel(
    const float* __restrict__ xyz, const float* __restrict__ scaling,
    const float* __restrict__ rotation, const float* __restrict__ opacity,
    const float* __restrict__ fdc, const float* __restrict__ frest,
    const float* __restrict__ vm, const float* __restrict__ pm,
    const float* __restrict__ campos, const float* __restrict__ bg,
    const int* __restrict__ pH, const int* __restrict__ pW,
    float* __restrict__ pre, float4* __restrict__ bboxpre,
    float* __restrict__ tzarr, int* __restrict__ rankpart,
    float* __restrict__ srt, float4* __restrict__ bboxsrt,
    float* __restrict__ part, float* __restrict__ out,
    float* __restrict__ radii_out, int N, int HW)
{
    cg::grid_group grid = cg::this_grid();
    const int bid = blockIdx.x;
    const int tid = threadIdx.x;
    const int nblk = gridDim.x;

    __shared__ float  s_fr[GPB_MAX * 45];
    __shared__ float  s_tz[SEG_L];
    __shared__ int    s_cnt[4];
    __shared__ int    s_idx[CHG];
    __shared__ float4 s_rec[3 * CHG];

    const int G  = (N + CHG - 1) / CHG;       // 8 chunks
    const int NT = (HW + 255) / 256;          // 64 tiles
    const int NB = (N + 255) / 256;           // 8 gaussian columns
    const int NJ = (N + SEG_L - 1) / SEG_L;   // 16 segments

    // ================= Phase 1: preprocess =================
    {
        int gpb = (N + nblk - 1) / nblk;      // 4
        int g0 = bid * gpb;
        int ng = N - g0; if (ng > gpb) ng = gpb; if (ng < 0) ng = 0;
        for (int t = tid; t < ng * 45; t += CHG)
            s_fr[t] = frest[(size_t)g0 * 45 + t];
        __syncthreads();

        if (tid < ng) {
            int i = g0 + tid;
            float H = (float)*pH, W = (float)*pW;

            float px_ = xyz[i*3+0], py_ = xyz[i*3+1], pz_ = xyz[i*3+2];
            float s0 = expf(scaling[i*3+0]), s1 = expf(scaling[i*3+1]), s2 = expf(scaling[i*3+2]);
            float op = 1.f / (1.f + expf(-opacity[i]));

            float qw = rotation[i*4+0], qx = rotation[i*4+1], qy = rotation[i*4+2], qz = rotation[i*4+3];
            float qn = fmaxf(sqrtf(qw*qw + qx*qx + qy*qy + qz*qz), 1e-12f);
            qw /= qn; qx /= qn; qy /= qn; qz /= qn;

            float R00 = 1.f - 2.f*(qy*qy + qz*qz), R01 = 2.f*(qx*qy - qw*qz), R02 = 2.f*(qx*qz + qw*qy);
            float R10 = 2.f*(qx*qy + qw*qz), R11 = 1.f - 2.f*(qx*qx + qz*qz), R12 = 2.f*(qy*qz - qw*qx);
            float R20 = 2.f*(qx*qz - qw*qy), R21 = 2.f*(qy*qz + qw*qx), R22 = 1.f - 2.f*(qx*qx + qy*qy);

            float M00 = R00*s0, M01 = R01*s1, M02 = R02*s2;
            float M10 = R10*s0, M11 = R11*s1, M12 = R12*s2;
            float M20 = R20*s0, M21 = R21*s1, M22 = R22*s2;

            float S00 = M00*M00 + M01*M01 + M02*M02;
            float S01 = M00*M10 + M01*M11 + M02*M12;
            float S02 = M00*M20 + M01*M21 + M02*M22;
            float S11 = M10*M10 + M11*M11 + M12*M12;
            float S12 = M10*M20 + M11*M21 + M12*M22;
            float S22 = M20*M20 + M21*M21 + M22*M22;

            float t0 = px_*vm[0] + py_*vm[4] + pz_*vm[8]  + vm[12];
            float t1 = px_*vm[1] + py_*vm[5] + pz_*vm[9]  + vm[13];
            float tz = px_*vm[2] + py_*vm[6] + pz_*vm[10] + vm[14];

            float fx = W / (2.f * TANFOV), fy = H / (2.f * TANFOV);
            float lim = 1.3f * TANFOV;
            float tzs = (fabsf(tz) > 1e-6f) ? tz : 1e-6f;
            float txz = fminf(fmaxf(t0 / tzs, -lim), lim) * tzs;
            float tyz = fminf(fmaxf(t1 / tzs, -lim), lim) * tzs;
            float J00 = fx / tzs, J02 = -fx * txz / (tzs * tzs);
            float J11 = fy / tzs, J12 = -fy * tyz / (tzs * tzs);

            float T00 = J00*vm[0] + J02*vm[2];
            float T01 = J00*vm[4] + J02*vm[6];
            float T02 = J00*vm[8] + J02*vm[10];
            float T10 = J11*vm[1] + J12*vm[2];
            float T11 = J11*vm[5] + J12*vm[6];
            float T12 = J11*vm[9] + J12*vm[10];

            float u0 = S00*T00 + S01*T01 + S02*T02;
            float u1 = S01*T00 + S11*T01 + S12*T02;
            float u2 = S02*T00 + S12*T01 + S22*T02;
            float v0 = S00*T10 + S01*T11 + S02*T12;
            float v1 = S01*T10 + S11*T11 + S12*T12;
            float v2 = S02*T10 + S12*T11 + S22*T12;
            float a  = T00*u0 + T01*u1 + T02*u2 + 0.3f;
            float b  = T10*u0 + T11*u1 + T12*u2;
            float c  = T10*v0 + T11*v1 + T12*v2 + 0.3f;

            float det = a*c - b*b;
            bool valid = (tz > 0.2f) && (det > 0.f);
            float inv_det = 1.f / ((det > 0.f) ? det : 1.f);
            float conA = c * inv_det, conB = -b * inv_det, conC = a * inv_det;
            float mid = 0.5f * (a + c);
            float lam = mid + sqrtf(fmaxf(mid*mid - det, 0.1f));
            radii_out[i] = valid ? ceilf(3.f * sqrtf(lam)) : 0.f;

            float h0 = px_*pm[0] + py_*pm[4] + pz_*pm[8]  + pm[12];
            float h1 = px_*pm[1] + py_*pm[5] + pz_*pm[9]  + pm[13];
            float h3 = px_*pm[3] + py_*pm[7] + pz_*pm[11] + pm[15];
            float pw = 1.f / (h3 + 1e-7f);
            float mx = ((h0*pw + 1.f) * W - 1.f) * 0.5f;
            float my = ((h1*pw + 1.f) * H - 1.f) * 0.5f;

            float ddx = px_ - campos[0], ddy = py_ - campos[1], ddz = pz_ - campos[2];
            float dn = fmaxf(sqrtf(ddx*ddx + ddy*ddy + ddz*ddz), 1e-12f);
            float x = ddx/dn, y = ddy/dn, z = ddz/dn;
            float xx = x*x, yy = y*y, zz = z*z, xy = x*y, yz = y*z, xz = x*z;

            float basis[16];
            basis[0]  = 0.28209479177387814f;
            basis[1]  = -0.4886025119029199f * y;
            basis[2]  =  0.4886025119029199f * z;
            basis[3]  = -0.4886025119029199f * x;
            basis[4]  =  1.0925484305920792f * xy;
            basis[5]  = -1.0925484305920792f * yz;
            basis[6]  =  0.31539156525252005f * (2.f*zz - xx - yy);
            basis[7]  = -1.0925484305920792f * xz;
            basis[8]  =  0.5462742152960396f * (xx - yy);
            basis[9]  = -0.5900435899266435f * y * (3.f*xx - yy);
            basis[10] =  2.890611442640554f  * xy * z;
            basis[11] = -0.4570457994644658f * y * (4.f*zz - xx - yy);
            basis[12] =  0.3731763325901154f * z * (2.f*zz - 3.f*xx - 3.f*yy);
            basis[13] = -0.4570457994644658f * x * (4.f*zz - xx - yy);
            basis[14] =  1.445305721320277f  * z * (xx - yy);
            basis[15] = -0.5900435899266435f * x * (xx - 3.f*yy);

            const float* fr = &s_fr[tid * 45];
            float col[3];
            #pragma unroll
            for (int ch = 0; ch < 3; ++ch) {
                float r = basis[0] * fdc[i*3 + ch];
                #pragma unroll
                for (int j = 1; j < 16; ++j)
                    r += basis[j] * fr[(j-1)*3 + ch];
                col[ch] = fmaxf(r + 0.5f, 0.f);
            }

            float opv = valid ? op : 0.f;
            float4* rec = (float4*)(pre + (size_t)i * REC);
            rec[0] = make_float4(tz, -0.5f*conA, -conB, -0.5f*conC);
            rec[1] = make_float4(mx, my, opv, 0.f);
            rec[2] = make_float4(col[0], col[1], col[2], 0.f);

            float4 bb;
            if (opv > 1.f/255.f) {
                float Rr = 1.01f * sqrtf(2.f * logf(255.f * opv) * lam) + 1.f;
                bb = make_float4(mx - Rr, mx + Rr, my - Rr, my + Rr);
            } else {
                bb = make_float4(1e30f, -1e30f, 1e30f, -1e30f);   // empty
            }
            bboxpre[i] = bb;
            tzarr[i] = tz;
        }
    }
    grid.sync();

    // ================= Phase 2: sort partial-rank count =================
    if (bid < NB * NJ) {
        int col = bid / NJ, seg = bid - col * NJ;
        int base = seg * SEG_L;
        for (int t = tid; t < SEG_L; t += CHG)
            s_tz[t] = (base + t < N) ? tzarr[base + t] : 3.4e38f;
        __syncthreads();

        int i = col * 256 + tid;
        if (i < N) {
            float key = tzarr[i];
            int cnt = 0;
            #pragma unroll 8
            for (int j = 0; j < SEG_L; j += 4) {
                float4 v = *reinterpret_cast<float4*>(&s_tz[j]);
                cnt += (v.x < key) || (v.x == key && (base + j)     < i);
                cnt += (v.y < key) || (v.y == key && (base + j + 1) < i);
                cnt += (v.z < key) || (v.z == key && (base + j + 2) < i);
                cnt += (v.w < key) || (v.w == key && (base + j + 3) < i);
            }
            rankpart[seg * N + i] = cnt;
        }
    }
    grid.sync();

    // ================= Phase 3: rank sum + scatter =================
    if (bid < NB) {
        int i = bid * 256 + tid;
        if (i < N) {
            int rank = 0;
            for (int s = 0; s < NJ; ++s) rank += rankpart[s * N + i];
            const float4* src = (const float4*)(pre + (size_t)i * REC);
            float4* dst = (float4*)(srt + (size_t)rank * REC);
            dst[0] = src[0]; dst[1] = src[1]; dst[2] = src[2];
            bboxsrt[rank] = bboxpre[i];
        }
    }
    grid.sync();

    // ================= Phase 4: tile-cull blend =================
    {
        const float4* grec = (const float4*)srt;
        int W = *pW;
        int tilesX = (W + 15) >> 4;
        int tile  = bid / G;
        int chunk = bid - tile * G;
        int tileX = tile % tilesX;
        int tileY = tile / tilesX;
        int px = (tileX << 4) + (tid & 15);
        int py = (tileY << 4) + (tid >> 4);
        int pix = py * W + px;
        float fpx = (float)px, fpy = (float)py;
        float ftx0 = (float)(tileX << 4), ftx1 = ftx0 + 15.f;
        float fty0 = (float)(tileY << 4), fty1 = fty0 + 15.f;
        int g0 = chunk * CHG;
        int S = G * HW;

        // cull: one bbox per thread, ballot-compact preserving depth order
        int g = g0 + tid;
        bool hit = false;
        if (g < N) {
            float4 bb = bboxsrt[g];
            hit = (bb.x <= ftx1) && (bb.y >= ftx0) &&
                  (bb.z <= fty1) && (bb.w >= fty0);
        }
        unsigned long long m = __ballot(hit);
        int lane = tid & 63, wv = tid >> 6;
        int pos = __popcll(m & ((1ull << lane) - 1ull));
        if (lane == 0) s_cnt[wv] = __popcll(m);
        __syncthreads();
        int total = s_cnt[0] + s_cnt[1] + s_cnt[2] + s_cnt[3];
        int off = 0;
        for (int w = 0; w < wv; ++w) off += s_cnt[w];
        if (hit) s_idx[off + pos] = g;
        __syncthreads();

        for (int k = tid; k < 3 * total; k += CHG) {
            int s = k / 3, e = k - 3 * s;
            s_rec[k] = grec[3 * s_idx[s] + e];
        }
        __syncthreads();

        float T = 1.f, c0 = 0.f, c1 = 0.f, c2 = 0.f, d = 0.f;
        for (int s = 0; s < total; ++s) {
            float4 pA = s_rec[3*s+0];   // tz, a2, b2, c2
            float4 pB = s_rec[3*s+1];   // mx, my, op, -
            float4 pC = s_rec[3*s+2];   // rgb
            float dx = fpx - pB.x, dy = fpy - pB.y;
            float power = pA.y*dx*dx + pA.w*dy*dy + pA.z*dx*dy;
            float alpha = fminf(0.99f, pB.z * __expf(fminf(power, 0.f)));
            bool keep = (power <= 0.f) && (alpha >= 1.f/255.f);
            float aeff = keep ? alpha : 0.f;
            float w = aeff * T;
            c0 = fmaf(w, pC.x, c0);
            c1 = fmaf(w, pC.y, c1);
            c2 = fmaf(w, pC.z, c2);
            d  = fmaf(w, pA.x, d);
            T  = T - aeff * T;
        }
        if (pix < HW) {
            int o = chunk * HW + pix;
            part[0*S+o] = c0; part[1*S+o] = c1; part[2*S+o] = c2;
            part[3*S+o] = d;  part[4*S+o] = T;
        }
    }
    grid.sync();

    // ================= Phase 5: per-tile combine =================
    if (bid < NT) {
        int pix = bid * 256 + tid;
        if (pix < HW) {
            int S = G * HW;
            float T = 1.f, c0 = 0.f, c1 = 0.f, c2 = 0.f, d = 0.f;
            for (int k = 0; k < G; ++k) {
                int o = k * HW + pix;
                c0 += T * part[0*S+o];
                c1 += T * part[1*S+o];
                c2 += T * part[2*S+o];
                d  += T * part[3*S+o];
                T  *= part[4*S+o];
            }
            out[0*HW+pix] = c0 + T*bg[0];
            out[1*HW+pix] = c1 + T*bg[1];
            out[2*HW+pix] = c2 + T*bg[2];
            out[3*HW+pix] = d;
            out[4*HW+pix] = 1.f - T;
        }
    }
}

extern "C" void kernel_launch(void* const* d_in, const int* in_sizes, int n_in,
                              void* d_out, int out_size, void* d_ws, size_t ws_size,
                              hipStream_t stream) {
    const float* xyz      = (const float*)d_in[0];
    const float* scaling  = (const float*)d_in[1];
    const float* rotation = (const float*)d_in[2];
    const float* opacity  = (const float*)d_in[3];
    const float* fdc      = (const float*)d_in[4];
    const float* frest    = (const float*)d_in[5];
    const float* vm       = (const float*)d_in[6];
    const float* pm       = (const float*)d_in[7];
    const float* campos   = (const float*)d_in[8];
    const float* bg       = (const float*)d_in[9];
    const int*   pH       = (const int*)d_in[10];
    const int*   pW       = (const int*)d_in[11];

    int N  = in_sizes[0] / 3;
    int HW = (out_size - N) / 5;
    int G  = (N + CHG - 1) / CHG;       // 8
    int NT = (HW + 255) / 256;          // 64
    int NJ = (N + SEG_L - 1) / SEG_L;   // 16
    int NBLK = NT * G;                  // 512 blocks

    // ws layout (floats unless noted):
    //   pre     : REC*N
    //   srt     : REC*N
    //   bboxpre : 4*N
    //   bboxsrt : 4*N
    //   tzarr   : N
    //   rankpart: NJ*N (ints)
    //   part    : 5*G*HW
    float*  ws       = (float*)d_ws;
    float*  pre      = ws;
    float*  srt      = pre + (size_t)REC * N;
    float4* bboxpre  = (float4*)(srt + (size_t)REC * N);
    float4* bboxsrt  = bboxpre + N;
    float*  tzarr    = (float*)(bboxsrt + N);
    int*    rankpart = (int*)(tzarr + N);
    float*  part     = (float*)(rankpart + (size_t)NJ * N);

    float* out   = (float*)d_out;
    float* radii = out + (size_t)5 * HW;

    void* args[] = {
        (void*)&xyz, (void*)&scaling, (void*)&rotation, (void*)&opacity,
        (void*)&fdc, (void*)&frest, (void*)&vm, (void*)&pm, (void*)&campos,
        (void*)&bg, (void*)&pH, (void*)&pW,
        (void*)&pre, (void*)&bboxpre, (void*)&tzarr, (void*)&rankpart,
        (void*)&srt, (void*)&bboxsrt, (void*)&part, (void*)&out,
        (void*)&radii, (void*)&N, (void*)&HW
    };
    hipLaunchCooperativeKernel((const void*)render_coop_kernel,
                               dim3(NBLK), dim3(CHG), args, 0, stream);
}

// Round 9
// 32.713 us; speedup vs baseline: 6.9778x; 6.9778x over previous
//
#include <hip/hip_runtime.h>
#include <math.h>

#define TANFOV 1.0f

// AoS gaussian record: 3 x float4 (in ORIGINAL gaussian order; depth order
// comes from the perm[] index array)
//   [0] = (tz, -0.5*conA, -conB, -0.5*conC)
//   [1] = (mx, my, op(0 if invalid), 0)
//   [2] = (c0, c1, c2, 0)
#define REC   12     // floats per gaussian
#define CHG   256    // gaussians per chunk (== block size)
#define SEG_L 128    // sort segment length

// ---------------------------------------------------------------------------
// Kernel A: role-split fused launch (no data dependency between roles):
//   blocks [0, NB)            : preprocess 256 gaussians each
//   blocks [NB, NB + NB*NJ)   : sort partial-rank count (col, seg)
// Count computes tz directly from xyz+vm (6 flops) instead of depending on
// preprocess output -- this is what makes the fusion legal.
// ---------------------------------------------------------------------------
__global__ __launch_bounds__(256)
void pre_count_kernel(
    const float* __restrict__ xyz, const float* __restrict__ scaling,
    const float* __restrict__ rotation, const float* __restrict__ opacity,
    const float* __restrict__ fdc, const float* __restrict__ frest,
    const float* __restrict__ vm, const float* __restrict__ pm,
    const float* __restrict__ campos,
    const int* __restrict__ pH, const int* __restrict__ pW,
    float* __restrict__ pre, float4* __restrict__ bboxpre,
    int* __restrict__ rankpart, float* __restrict__ radii_out,
    int N, int NB, int NJ)
{
    __shared__ float s_fr[256 * 45];      // preprocess: frest staging (46 KB)
    const int tid = threadIdx.x;
    const int bid = blockIdx.x;

    if (bid >= NB) {
        // ================= role: sort partial-rank count =================
        float* s_tz = s_fr;               // alias (only SEG_L floats used)
        int t = bid - NB;
        int col = t / NJ, seg = t - col * NJ;
        int base = seg * SEG_L;
        float c2 = vm[2], c6 = vm[6], c10 = vm[10], c14 = vm[14];
        if (tid < SEG_L) {
            int j = base + tid;
            s_tz[tid] = (j < N)
                ? xyz[j*3+0]*c2 + xyz[j*3+1]*c6 + xyz[j*3+2]*c10 + c14
                : 3.4e38f;
        }
        __syncthreads();

        int i = col * 256 + tid;
        if (i < N) {
            float key = xyz[i*3+0]*c2 + xyz[i*3+1]*c6 + xyz[i*3+2]*c10 + c14;
            int cnt = 0;
            #pragma unroll 8
            for (int j = 0; j < SEG_L; j += 4) {
                float4 v = *reinterpret_cast<float4*>(&s_tz[j]);
                cnt += (v.x < key) || (v.x == key && (base + j)     < i);
                cnt += (v.y < key) || (v.y == key && (base + j + 1) < i);
                cnt += (v.z < key) || (v.z == key && (base + j + 2) < i);
                cnt += (v.w < key) || (v.w == key && (base + j + 3) < i);
            }
            rankpart[seg * N + i] = cnt;
        }
        return;
    }

    // ================= role: preprocess =================
    int i0 = bid * 256;
    int cnt = N - i0; if (cnt > 256) cnt = 256;
    for (int t = tid; t < cnt * 45; t += 256)
        s_fr[t] = frest[(size_t)i0 * 45 + t];
    __syncthreads();

    int i = i0 + tid;
    if (i >= N) return;
    float H = (float)*pH, W = (float)*pW;

    float px_ = xyz[i*3+0], py_ = xyz[i*3+1], pz_ = xyz[i*3+2];
    float s0 = expf(scaling[i*3+0]), s1 = expf(scaling[i*3+1]), s2 = expf(scaling[i*3+2]);
    float op = 1.f / (1.f + expf(-opacity[i]));

    float qw = rotation[i*4+0], qx = rotation[i*4+1], qy = rotation[i*4+2], qz = rotation[i*4+3];
    float qn = fmaxf(sqrtf(qw*qw + qx*qx + qy*qy + qz*qz), 1e-12f);
    qw /= qn; qx /= qn; qy /= qn; qz /= qn;

    float R00 = 1.f - 2.f*(qy*qy + qz*qz), R01 = 2.f*(qx*qy - qw*qz), R02 = 2.f*(qx*qz + qw*qy);
    float R10 = 2.f*(qx*qy + qw*qz), R11 = 1.f - 2.f*(qx*qx + qz*qz), R12 = 2.f*(qy*qz - qw*qx);
    float R20 = 2.f*(qx*qz - qw*qy), R21 = 2.f*(qy*qz + qw*qx), R22 = 1.f - 2.f*(qx*qx + qy*qy);

    float M00 = R00*s0, M01 = R01*s1, M02 = R02*s2;
    float M10 = R10*s0, M11 = R11*s1, M12 = R12*s2;
    float M20 = R20*s0, M21 = R21*s1, M22 = R22*s2;

    float S00 = M00*M00 + M01*M01 + M02*M02;
    float S01 = M00*M10 + M01*M11 + M02*M12;
    float S02 = M00*M20 + M01*M21 + M02*M22;
    float S11 = M10*M10 + M11*M11 + M12*M12;
    float S12 = M10*M20 + M11*M21 + M12*M22;
    float S22 = M20*M20 + M21*M21 + M22*M22;

    float t0 = px_*vm[0] + py_*vm[4] + pz_*vm[8]  + vm[12];
    float t1 = px_*vm[1] + py_*vm[5] + pz_*vm[9]  + vm[13];
    float tz = px_*vm[2] + py_*vm[6] + pz_*vm[10] + vm[14];

    float fx = W / (2.f * TANFOV), fy = H / (2.f * TANFOV);
    float lim = 1.3f * TANFOV;
    float tzs = (fabsf(tz) > 1e-6f) ? tz : 1e-6f;
    float txz = fminf(fmaxf(t0 / tzs, -lim), lim) * tzs;
    float tyz = fminf(fmaxf(t1 / tzs, -lim), lim) * tzs;
    float J00 = fx / tzs, J02 = -fx * txz / (tzs * tzs);
    float J11 = fy / tzs, J12 = -fy * tyz / (tzs * tzs);

    float T00 = J00*vm[0] + J02*vm[2];
    float T01 = J00*vm[4] + J02*vm[6];
    float T02 = J00*vm[8] + J02*vm[10];
    float T10 = J11*vm[1] + J12*vm[2];
    float T11 = J11*vm[5] + J12*vm[6];
    float T12 = J11*vm[9] + J12*vm[10];

    float u0 = S00*T00 + S01*T01 + S02*T02;
    float u1 = S01*T00 + S11*T01 + S12*T02;
    float u2 = S02*T00 + S12*T01 + S22*T02;
    float v0 = S00*T10 + S01*T11 + S02*T12;
    float v1 = S01*T10 + S11*T11 + S12*T12;
    float v2 = S02*T10 + S12*T11 + S22*T12;
    float a  = T00*u0 + T01*u1 + T02*u2 + 0.3f;
    float b  = T10*u0 + T11*u1 + T12*u2;
    float c  = T10*v0 + T11*v1 + T12*v2 + 0.3f;

    float det = a*c - b*b;
    bool valid = (tz > 0.2f) && (det > 0.f);
    float inv_det = 1.f / ((det > 0.f) ? det : 1.f);
    float conA = c * inv_det, conB = -b * inv_det, conC = a * inv_det;
    float mid = 0.5f * (a + c);
    float lam = mid + sqrtf(fmaxf(mid*mid - det, 0.1f));
    radii_out[i] = valid ? ceilf(3.f * sqrtf(lam)) : 0.f;

    float h0 = px_*pm[0] + py_*pm[4] + pz_*pm[8]  + pm[12];
    float h1 = px_*pm[1] + py_*pm[5] + pz_*pm[9]  + pm[13];
    float h3 = px_*pm[3] + py_*pm[7] + pz_*pm[11] + pm[15];
    float pw = 1.f / (h3 + 1e-7f);
    float mx = ((h0*pw + 1.f) * W - 1.f) * 0.5f;
    float my = ((h1*pw + 1.f) * H - 1.f) * 0.5f;

    float ddx = px_ - campos[0], ddy = py_ - campos[1], ddz = pz_ - campos[2];
    float dn = fmaxf(sqrtf(ddx*ddx + ddy*ddy + ddz*ddz), 1e-12f);
    float x = ddx/dn, y = ddy/dn, z = ddz/dn;
    float xx = x*x, yy = y*y, zz = z*z, xy = x*y, yz = y*z, xz = x*z;

    float basis[16];
    basis[0]  = 0.28209479177387814f;
    basis[1]  = -0.4886025119029199f * y;
    basis[2]  =  0.4886025119029199f * z;
    basis[3]  = -0.4886025119029199f * x;
    basis[4]  =  1.0925484305920792f * xy;
    basis[5]  = -1.0925484305920792f * yz;
    basis[6]  =  0.31539156525252005f * (2.f*zz - xx - yy);
    basis[7]  = -1.0925484305920792f * xz;
    basis[8]  =  0.5462742152960396f * (xx - yy);
    basis[9]  = -0.5900435899266435f * y * (3.f*xx - yy);
    basis[10] =  2.890611442640554f  * xy * z;
    basis[11] = -0.4570457994644658f * y * (4.f*zz - xx - yy);
    basis[12] =  0.3731763325901154f * z * (2.f*zz - 3.f*xx - 3.f*yy);
    basis[13] = -0.4570457994644658f * x * (4.f*zz - xx - yy);
    basis[14] =  1.445305721320277f  * z * (xx - yy);
    basis[15] = -0.5900435899266435f * x * (xx - 3.f*yy);

    const float* fr = &s_fr[tid * 45];
    float col[3];
    #pragma unroll
    for (int ch = 0; ch < 3; ++ch) {
        float r = basis[0] * fdc[i*3 + ch];
        #pragma unroll
        for (int j = 1; j < 16; ++j)
            r += basis[j] * fr[(j-1)*3 + ch];
        col[ch] = fmaxf(r + 0.5f, 0.f);
    }

    float opv = valid ? op : 0.f;
    float4* rec = (float4*)(pre + (size_t)i * REC);
    rec[0] = make_float4(tz, -0.5f*conA, -conB, -0.5f*conC);
    rec[1] = make_float4(mx, my, opv, 0.f);
    rec[2] = make_float4(col[0], col[1], col[2], 0.f);

    float4 bb;
    if (opv > 1.f/255.f) {
        float Rr = 1.01f * sqrtf(2.f * logf(255.f * opv) * lam) + 1.f;
        bb = make_float4(mx - Rr, mx + Rr, my - Rr, my + Rr);
    } else {
        bb = make_float4(1e30f, -1e30f, 1e30f, -1e30f);   // empty
    }
    bboxpre[i] = bb;
}

// ---------------------------------------------------------------------------
// Kernel B: rank sum -> permutation (perm[rank] = original index).
// ---------------------------------------------------------------------------
__global__ void scatter_kernel(const int* __restrict__ rankpart,
                               int* __restrict__ perm, int N, int NJ)
{
    int i = blockIdx.x * blockDim.x + threadIdx.x;
    if (i >= N) return;
    int rank = 0;
    for (int s = 0; s < NJ; ++s) rank += rankpart[s * N + i];
    perm[rank] = i;
}

// ---------------------------------------------------------------------------
// Kernel C: tile-cull blend. Block = (16x16 tile, 256-gaussian depth chunk).
// Phase A: thread t tests sorted slot g0+t: orig = perm[g], bbox gather,
// ballot-compact survivor ORIGINAL indices in depth order. Phase B: stage
// survivor records from pre (parallel gathers). Blend per pixel over
// survivors; write chunk partials.
// part layout: field*(G*HW) + chunk*HW + pix; fields 0..2 color, 3 depth, 4 T
// ---------------------------------------------------------------------------
__global__ void blend1_kernel(const float4* __restrict__ grec,
                              const float4* __restrict__ bbox,
                              const int* __restrict__ perm,
                              const int* __restrict__ pW,
                              float* __restrict__ part,
                              int N, int HW, int G)
{
    __shared__ int    s_cnt[4];
    __shared__ int    s_idx[CHG];
    __shared__ float4 s_rec[3 * CHG];

    int tid = threadIdx.x;
    int W = *pW;
    int tilesX = (W + 15) >> 4;
    int tileX = blockIdx.x % tilesX;
    int tileY = blockIdx.x / tilesX;
    int px = (tileX << 4) + (tid & 15);
    int py = (tileY << 4) + (tid >> 4);
    int pix = py * W + px;
    float fpx = (float)px, fpy = (float)py;
    float ftx0 = (float)(tileX << 4), ftx1 = ftx0 + 15.f;
    float fty0 = (float)(tileY << 4), fty1 = fty0 + 15.f;

    int chunk = blockIdx.y;
    int g0 = chunk * CHG;
    int S = G * HW;

    // ---- Phase A: cull (depth-ordered via perm) ----
    int g = g0 + tid;
    bool hit = false;
    int orig = 0;
    if (g < N) {
        orig = perm[g];                      // coalesced int load
        float4 bb = bbox[orig];              // gathered 16B load (L2)
        hit = (bb.x <= ftx1) && (bb.y >= ftx0) &&
              (bb.z <= fty1) && (bb.w >= fty0);
    }
    unsigned long long m = __ballot(hit);
    int lane = tid & 63, wv = tid >> 6;
    int pos = __popcll(m & ((1ull << lane) - 1ull));
    if (lane == 0) s_cnt[wv] = __popcll(m);
    __syncthreads();
    int total = s_cnt[0] + s_cnt[1] + s_cnt[2] + s_cnt[3];
    int off = 0;
    for (int w = 0; w < wv; ++w) off += s_cnt[w];
    if (hit) s_idx[off + pos] = orig;
    __syncthreads();

    // ---- Phase B: stage survivor records (gathers, parallel across threads)
    for (int k = tid; k < 3 * total; k += CHG) {
        int s = k / 3, e = k - 3 * s;
        s_rec[k] = grec[3 * s_idx[s] + e];
    }
    __syncthreads();

    // ---- blend over survivors (depth order preserved) ----
    float T = 1.f, c0 = 0.f, c1 = 0.f, c2 = 0.f, d = 0.f;
    for (int s = 0; s < total; ++s) {
        float4 pA = s_rec[3*s+0];   // tz, a2, b2, c2
        float4 pB = s_rec[3*s+1];   // mx, my, op, -
        float4 pC = s_rec[3*s+2];   // rgb
        float dx = fpx - pB.x, dy = fpy - pB.y;
        float power = pA.y*dx*dx + pA.w*dy*dy + pA.z*dx*dy;
        float alpha = fminf(0.99f, pB.z * __expf(fminf(power, 0.f)));
        bool keep = (power <= 0.f) && (alpha >= 1.f/255.f);
        float aeff = keep ? alpha : 0.f;
        float w = aeff * T;
        c0 = fmaf(w, pC.x, c0);
        c1 = fmaf(w, pC.y, c1);
        c2 = fmaf(w, pC.z, c2);
        d  = fmaf(w, pA.x, d);
        T  = T - aeff * T;
    }
    if (pix < HW) {
        int o = chunk * HW + pix;
        part[0*S+o] = c0; part[1*S+o] = c1; part[2*S+o] = c2;
        part[3*S+o] = d;  part[4*S+o] = T;
    }
}

// ---------------------------------------------------------------------------
// Kernel D: combine chunks per pixel, write final outputs.
// out layout: color[3][HW], depth[HW], amap[HW]  (radii written by kernel A)
// ---------------------------------------------------------------------------
__global__ void blend2_kernel(const float* __restrict__ part,
                              const float* __restrict__ bg,
                              float* __restrict__ out, int HW, int G)
{
    int pix = blockIdx.x * blockDim.x + threadIdx.x;
    if (pix >= HW) return;
    int S = G * HW;
    float T = 1.f, c0 = 0.f, c1 = 0.f, c2 = 0.f, d = 0.f;
    for (int k = 0; k < G; ++k) {
        int o = k * HW + pix;
        c0 += T * part[0*S+o];
        c1 += T * part[1*S+o];
        c2 += T * part[2*S+o];
        d  += T * part[3*S+o];
        T  *= part[4*S+o];
    }
    out[0*HW+pix] = c0 + T*bg[0];
    out[1*HW+pix] = c1 + T*bg[1];
    out[2*HW+pix] = c2 + T*bg[2];
    out[3*HW+pix] = d;
    out[4*HW+pix] = 1.f - T;
}

extern "C" void kernel_launch(void* const* d_in, const int* in_sizes, int n_in,
                              void* d_out, int out_size, void* d_ws, size_t ws_size,
                              hipStream_t stream) {
    const float* xyz      = (const float*)d_in[0];
    const float* scaling  = (const float*)d_in[1];
    const float* rotation = (const float*)d_in[2];
    const float* opacity  = (const float*)d_in[3];
    const float* fdc      = (const float*)d_in[4];
    const float* frest    = (const float*)d_in[5];
    const float* vm       = (const float*)d_in[6];
    const float* pm       = (const float*)d_in[7];
    const float* campos   = (const float*)d_in[8];
    const float* bg       = (const float*)d_in[9];
    const int*   pH       = (const int*)d_in[10];
    const int*   pW       = (const int*)d_in[11];

    int N  = in_sizes[0] / 3;
    int HW = (out_size - N) / 5;
    int G  = (N + CHG - 1) / CHG;       // 8 chunks
    int NJ = (N + SEG_L - 1) / SEG_L;   // 16 segments
    int NB = (N + 255) / 256;           // 8 columns
    int NT = (HW + 255) / 256;          // 64 tiles

    // ws layout:
    //   pre     : REC*N floats
    //   bboxpre : 4*N floats
    //   rankpart: NJ*N ints
    //   perm    : N ints
    //   part    : 5*G*HW floats
    float*  ws       = (float*)d_ws;
    float*  pre      = ws;
    float4* bboxpre  = (float4*)(pre + (size_t)REC * N);
    int*    rankpart = (int*)(bboxpre + N);
    int*    perm     = rankpart + (size_t)NJ * N;
    float*  part     = (float*)(perm + N);

    float* out   = (float*)d_out;
    float* radii = out + (size_t)5 * HW;

    // Kernel A: preprocess (blocks 0..NB-1)  ||  count (blocks NB..NB+NB*NJ-1)
    pre_count_kernel<<<NB + NB * NJ, 256, 0, stream>>>(
        xyz, scaling, rotation, opacity, fdc, frest, vm, pm, campos, pH, pW,
        pre, bboxpre, rankpart, radii, N, NB, NJ);
    // Kernel B: ranks -> permutation
    scatter_kernel<<<NB, 256, 0, stream>>>(rankpart, perm, N, NJ);
    // Kernel C: tile-cull blend
    dim3 bgrid(NT, G);
    blend1_kernel<<<bgrid, CHG, 0, stream>>>(
        (const float4*)pre, bboxpre, perm, pW, part, N, HW, G);
    // Kernel D: combine
    blend2_kernel<<<NT, 256, 0, stream>>>(part, bg, out, HW, G);
}